// Round 14
// baseline (209.806 us; speedup 1.0000x reference)
//
#include <hip/hip_runtime.h>

// ---- problem geometry ----
#define D_MODEL 512
#define HD      1960
#define NPAD    2048          // HD padded to tile multiple
#define NVECS   720
#define MROWS   14400         // 4*3600
#define MPAD    14464         // 113*128
#define HP      66
#define WP      114
#define IMGPIX  7524          // HP*WP

typedef __bf16 bf16x8 __attribute__((ext_vector_type(8)));
typedef float  f32x4  __attribute__((ext_vector_type(4)));

__device__ __forceinline__ unsigned short f2bf(float f) {
    unsigned u = __builtin_bit_cast(unsigned, f);
    u += 0x7FFFu + ((u >> 16) & 1u);   // RNE
    return (unsigned short)(u >> 16);
}
__device__ __forceinline__ float bf2f(unsigned short s) {
    unsigned u = ((unsigned)s) << 16;
    return __builtin_bit_cast(float, u);
}

__device__ __forceinline__ void gload_lds16(const unsigned short* g, unsigned short* l) {
    __builtin_amdgcn_global_load_lds(
        (const __attribute__((address_space(1))) unsigned int*)g,
        (__attribute__((address_space(3))) unsigned int*)l,
        16, 0, 0);
}

// ---- convert x (fp32) -> bf16, zero-pad rows [14400,14464) ----
__global__ void cvt_x(const float* __restrict__ x, unsigned short* __restrict__ xb) {
    size_t i = ((size_t)blockIdx.x * 256 + threadIdx.x) * 4;
    const size_t valid = (size_t)MROWS * D_MODEL;
    if (i >= (size_t)MPAD * D_MODEL) return;
    ushort4 o;
    if (i < valid) {
        float4 v = *(const float4*)(x + i);
        o.x = f2bf(v.x); o.y = f2bf(v.y); o.z = f2bf(v.z); o.w = f2bf(v.w);
    } else {
        o.x = o.y = o.z = o.w = 0;
    }
    *(ushort4*)(xb + i) = o;
}

// ---- tiled transpose + fp32->bf16, zero-fill outside src ----
__global__ void transpose_cvt(const float* __restrict__ src, unsigned short* __restrict__ dst,
                              int srcR, int srcC, int dstR, int dstC) {
    __shared__ float tile[32][33];
    int c0 = blockIdx.x * 32;
    int r0 = blockIdx.y * 32;
    int tx = threadIdx.x, ty = threadIdx.y;   // (32,8)
    #pragma unroll
    for (int i = 0; i < 32; i += 8) {
        int sr = c0 + ty + i, sc = r0 + tx;
        tile[ty + i][tx] = (sr < srcR && sc < srcC) ? src[(size_t)sr * srcC + sc] : 0.f;
    }
    __syncthreads();
    #pragma unroll
    for (int i = 0; i < 32; i += 8) {
        int dr = r0 + ty + i, dc = c0 + tx;
        if (dr < dstR && dc < dstC)
            dst[(size_t)dr * dstC + dc] = f2bf(tile[tx][ty + i]);
    }
}

// ---- 128x128 BK=64 double-buffered counted-vmcnt bf16 GEMM (R12, GEMM1 only) ----
// MODE 0: out bf16 TRANSPOSED  hT[col*MPAD + row], skip cols >= validN
template<int MODE>
__global__ __launch_bounds__(256) void gemm_bt(const unsigned short* __restrict__ A,
                        const unsigned short* __restrict__ BT,
                        const float* __restrict__ bias,
                        void* __restrict__ Cout,
                        int K, int ldc, int validN, int validM) {
    __shared__ unsigned short lds[2][16384];   // 64KB total
    const int t    = threadIdx.x;
    const int wid  = t >> 6, lane = t & 63;
    const int wr   = wid >> 1, wc = wid & 1;
    const int lr   = lane & 15, lh = lane >> 4;
    const int m0   = blockIdx.y * 128, n0 = blockIdx.x * 128;

    int rr[4], qq[4];
    #pragma unroll
    for (int i = 0; i < 4; ++i) {
        int c = t + i * 256;
        rr[i] = c >> 3;
        qq[i] = (c & 7) ^ (rr[i] & 7);
    }

#define STAGE(buf, kt) do { \
        unsigned short* LA = &lds[buf][0]; \
        unsigned short* LB = &lds[buf][8192]; \
        _Pragma("unroll") \
        for (int i = 0; i < 4; ++i) { \
            gload_lds16(A  + (size_t)(m0 + rr[i]) * K + (kt) + qq[i] * 8, LA + (t + i * 256) * 8); \
            gload_lds16(BT + (size_t)(n0 + rr[i]) * K + (kt) + qq[i] * 8, LB + (t + i * 256) * 8); \
        } \
    } while (0)

    f32x4 acc[4][4] = {};
    const int NT = K >> 6;

    STAGE(0, 0);
    for (int tt = 0; tt < NT; ++tt) {
        if (tt + 1 < NT) {
            STAGE((tt + 1) & 1, (tt + 1) * 64);
            asm volatile("s_waitcnt vmcnt(8)" ::: "memory");
        } else {
            asm volatile("s_waitcnt vmcnt(0)" ::: "memory");
        }
        __builtin_amdgcn_s_barrier();
        __builtin_amdgcn_sched_barrier(0);
        const unsigned short* La = &lds[tt & 1][0];
        const unsigned short* Lb = &lds[tt & 1][8192];
        #pragma unroll
        for (int ks = 0; ks < 2; ++ks) {
            bf16x8 a[4], b[4];
            #pragma unroll
            for (int f = 0; f < 4; ++f) {
                int row = wr * 64 + f * 16 + lr;
                int sl  = (ks * 4 + lh) ^ (lr & 7);
                a[f] = *(const bf16x8*)(La + row * 64 + sl * 8);
            }
            #pragma unroll
            for (int g = 0; g < 4; ++g) {
                int row = wc * 64 + g * 16 + lr;
                int sl  = (ks * 4 + lh) ^ (lr & 7);
                b[g] = *(const bf16x8*)(Lb + row * 64 + sl * 8);
            }
            __builtin_amdgcn_s_setprio(1);
            #pragma unroll
            for (int fm = 0; fm < 4; ++fm)
                #pragma unroll
                for (int fn = 0; fn < 4; ++fn)
                    acc[fm][fn] = __builtin_amdgcn_mfma_f32_16x16x32_bf16(
                        a[fm], b[fn], acc[fm][fn], 0, 0, 0);
            __builtin_amdgcn_s_setprio(0);
        }
        __builtin_amdgcn_s_barrier();
        __builtin_amdgcn_sched_barrier(0);
    }
#undef STAGE

    // C/D layout: col=lane&15, row=(lane>>4)*4+j  [m89 verified]
    if (MODE == 0) {
        unsigned short* smem = &lds[0][0];
        #pragma unroll
        for (int fm = 0; fm < 4; ++fm) {
            #pragma unroll
            for (int fn = 0; fn < 4; ++fn) {
                int lcol = wc * 64 + fn * 16 + lr;
                float bv = bias[n0 + lcol];
                #pragma unroll
                for (int j = 0; j < 4; ++j) {
                    int lrow = wr * 64 + fm * 16 + lh * 4 + j;
                    smem[lcol * 128 + (lrow ^ ((lcol & 15) << 3))] =
                        f2bf(acc[fm][fn][j] + bv);
                }
            }
        }
        __syncthreads();
        unsigned short* hT = (unsigned short*)Cout;
        int col = t >> 1, half = t & 1;
        int gcol = n0 + col;
        if (gcol < validN) {
            #pragma unroll
            for (int r = 0; r < 16; ++r) {
                int row = half * 64 + r * 4;
                ushort4 v4 = *(const ushort4*)&smem[col * 128 + (row ^ ((col & 15) << 3))];
                *(ushort4*)&hT[(size_t)gcol * MPAD + m0 + row] = v4;
            }
        }
    } else {
        #pragma unroll
        for (int fm = 0; fm < 4; ++fm) {
            #pragma unroll
            for (int fn = 0; fn < 4; ++fn) {
                int gcol = n0 + wc * 64 + fn * 16 + lr;
                float bv = bias[gcol];
                #pragma unroll
                for (int j = 0; j < 4; ++j) {
                    int grow = m0 + wr * 64 + fm * 16 + lh * 4 + j;
                    if (grow < validM)
                        ((float*)Cout)[(size_t)grow * ldc + gcol] = acc[fm][fn][j] + bv;
                }
            }
        }
    }
}

// ---- 128x64 BK=64 counted-vmcnt bf16 GEMM for GEMM2 (3 blocks/CU) ----
// C = A(MxK) * BT(NxK)^T + bias, fp32 row-major out (ldc=512), skip rows >= validM.
// 4 waves (2x2), wave tile 64x32, acc 4x2. LDS 48KB = 2 bufs x [A 16KB | B 8KB],
// slot-XOR layout; staging 6 loads/thread; vmcnt(6) counted in-loop.
__global__ __launch_bounds__(256) void gemm_n64(const unsigned short* __restrict__ A,
                        const unsigned short* __restrict__ BT,
                        const float* __restrict__ bias,
                        float* __restrict__ out,
                        int K, int validM) {
    __shared__ unsigned short lds[2][12288];   // 48KB total
    const int t    = threadIdx.x;
    const int wid  = t >> 6, lane = t & 63;
    const int wr   = wid >> 1, wc = wid & 1;
    const int lr   = lane & 15, lh = lane >> 4;
    const int m0   = blockIdx.y * 128, n0 = blockIdx.x * 64;

    // A tile: 1024 chunks (128 rows x 8 slots); thread owns c = t + i*256, i=0..3
    int rA[4], qA[4];
    #pragma unroll
    for (int i = 0; i < 4; ++i) {
        int c = t + i * 256;
        rA[i] = c >> 3;
        qA[i] = (c & 7) ^ (rA[i] & 7);
    }
    // B tile: 512 chunks (64 rows x 8 slots); thread owns c = t, t+256
    int rB[2], qB[2];
    #pragma unroll
    for (int i = 0; i < 2; ++i) {
        int c = t + i * 256;
        rB[i] = c >> 3;
        qB[i] = (c & 7) ^ (rB[i] & 7);
    }

#define STAGE64(buf, kt) do { \
        unsigned short* LA = &lds[buf][0]; \
        unsigned short* LB = &lds[buf][8192]; \
        _Pragma("unroll") \
        for (int i = 0; i < 4; ++i) \
            gload_lds16(A  + (size_t)(m0 + rA[i]) * K + (kt) + qA[i] * 8, LA + (t + i * 256) * 8); \
        _Pragma("unroll") \
        for (int i = 0; i < 2; ++i) \
            gload_lds16(BT + (size_t)(n0 + rB[i]) * K + (kt) + qB[i] * 8, LB + (t + i * 256) * 8); \
    } while (0)

    f32x4 acc[4][2] = {};
    const int NT = K >> 6;

    STAGE64(0, 0);
    for (int tt = 0; tt < NT; ++tt) {
        if (tt + 1 < NT) {
            STAGE64((tt + 1) & 1, (tt + 1) * 64);
            asm volatile("s_waitcnt vmcnt(6)" ::: "memory");
        } else {
            asm volatile("s_waitcnt vmcnt(0)" ::: "memory");
        }
        __builtin_amdgcn_s_barrier();
        __builtin_amdgcn_sched_barrier(0);
        const unsigned short* La = &lds[tt & 1][0];
        const unsigned short* Lb = &lds[tt & 1][8192];
        #pragma unroll
        for (int ks = 0; ks < 2; ++ks) {
            bf16x8 a[4], b[2];
            #pragma unroll
            for (int f = 0; f < 4; ++f) {
                int row = wr * 64 + f * 16 + lr;
                int sl  = (ks * 4 + lh) ^ (lr & 7);
                a[f] = *(const bf16x8*)(La + row * 64 + sl * 8);
            }
            #pragma unroll
            for (int g = 0; g < 2; ++g) {
                int row = wc * 32 + g * 16 + lr;
                int sl  = (ks * 4 + lh) ^ (lr & 7);
                b[g] = *(const bf16x8*)(Lb + row * 64 + sl * 8);
            }
            __builtin_amdgcn_s_setprio(1);
            #pragma unroll
            for (int fm = 0; fm < 4; ++fm)
                #pragma unroll
                for (int fn = 0; fn < 2; ++fn)
                    acc[fm][fn] = __builtin_amdgcn_mfma_f32_16x16x32_bf16(
                        a[fm], b[fn], acc[fm][fn], 0, 0, 0);
            __builtin_amdgcn_s_setprio(0);
        }
        __builtin_amdgcn_s_barrier();
        __builtin_amdgcn_sched_barrier(0);
    }
#undef STAGE64

    // C/D layout: col=lane&15, row=(lane>>4)*4+j
    #pragma unroll
    for (int fm = 0; fm < 4; ++fm) {
        #pragma unroll
        for (int fn = 0; fn < 2; ++fn) {
            int gcol = n0 + wc * 32 + fn * 16 + lr;
            float bv = bias[gcol];
            #pragma unroll
            for (int j = 0; j < 4; ++j) {
                int grow = m0 + wr * 64 + fm * 16 + lh * 4 + j;
                if (grow < validM)
                    out[(size_t)grow * 512 + gcol] = acc[fm][fn][j] + bv;
            }
        }
    }
}

// ---- fold + normalize + relu -> per-(b2,c) padded image (bf16) ----
__global__ void fold_norm(const unsigned short* __restrict__ hT, unsigned short* __restrict__ img2) {
    int y  = blockIdx.x;
    int g  = blockIdx.y;
    int b2 = g / 10, cg = g % 10;
    int c0 = cg * 4;
    int x  = threadIdx.x;
    if (x >= WP) return;
    float val[4] = {0.f, 0.f, 0.f, 0.f};
    if (y >= 3 && y < 63 && x >= 3 && x < 111) {
        int kiA[3], biA[3], nki = 0;
        for (int ki = y % 3; ki < 7; ki += 3) {
            int bi = (y - ki) / 3;
            if (y - ki >= 0 && bi < 20) { kiA[nki] = ki; biA[nki] = bi; ++nki; }
        }
        int kjA[3], bjA[3], nkj = 0;
        for (int kj = x % 3; kj < 7; kj += 3) {
            int bj = (x - kj) / 3;
            if (x - kj >= 0 && bj < 36) { kjA[nkj] = kj; bjA[nkj] = bj; ++nkj; }
        }
        float s[4] = {0.f, 0.f, 0.f, 0.f};
        for (int i = 0; i < nki; ++i) {
            for (int j = 0; j < nkj; ++j) {
                int row = b2 * NVECS + biA[i] * 36 + bjA[j];
                int colb = kiA[i] * 7 + kjA[j];
                #pragma unroll
                for (int q = 0; q < 4; ++q)
                    s[q] += bf2f(hT[(size_t)((c0 + q) * 49 + colb) * MPAD + row]);
            }
        }
        float inv = 1.f / (float)(nki * nkj);
        #pragma unroll
        for (int q = 0; q < 4; ++q)
            val[q] = fmaxf(s[q] * inv, 0.f);
    }
    #pragma unroll
    for (int q = 0; q < 4; ++q)
        img2[(size_t)(b2 * 40 + c0 + q) * IMGPIX + y * WP + x] = f2bf(val[q]);
}

// ---- unfold, LDS-staged ----
__global__ void unfold_k(const unsigned short* __restrict__ img2, unsigned short* __restrict__ h2b) {
    __shared__ unsigned short lds[20 * 798];
    __shared__ unsigned short lut[980];
    const int gb = blockIdx.x;                 // b2*20 + bi
    const int cg = blockIdx.y;
    const int b2 = gb / 20, bi = gb % 20;
    const int t  = threadIdx.x;

    const unsigned short* src = img2 + (size_t)(b2 * 40 + cg * 20) * IMGPIX + (bi * 3) * WP;
    for (int p = t; p < 7980; p += 256) {
        int cc = p / 399, rem2 = p - cc * 399;
        *(ushort2*)&lds[cc * 798 + rem2 * 2] =
            *(const ushort2*)&src[(size_t)cc * IMGPIX + rem2 * 2];
    }
    for (int L = t; L < 980; L += 256) {
        int cc = L / 49, kk = L - cc * 49;
        lut[L] = (unsigned short)(cc * 798 + (kk / 7) * 114 + (kk % 7));
    }
    __syncthreads();

    const int cpr   = (cg == 0) ? 245 : 267;
    const int total = 36 * cpr;
    const int rowbase = b2 * NVECS + bi * 36;
    const int hdbase  = cg * 980;
    for (int i = t; i < total; i += 256) {
        int r = i / cpr, q = i - r * cpr;
        int hl = q * 4;
        ushort4 v;
        unsigned short* vv = (unsigned short*)&v;
        #pragma unroll
        for (int e = 0; e < 4; ++e) {
            int h = hl + e;
            vv[e] = (h < 980) ? lds[lut[h] + r * 3] : (unsigned short)0;
        }
        *(ushort4*)&h2b[(size_t)(rowbase + r) * NPAD + hdbase + hl] = v;
    }
}

extern "C" void kernel_launch(void* const* d_in, const int* in_sizes, int n_in,
                              void* d_out, int out_size, void* d_ws, size_t ws_size,
                              hipStream_t stream) {
    const float* x  = (const float*)d_in[0];
    const float* W1 = (const float*)d_in[1];
    const float* b1 = (const float*)d_in[2];
    const float* W2 = (const float*)d_in[3];
    const float* b2 = (const float*)d_in[4];
    float* out = (float*)d_out;

    unsigned short* xb   = (unsigned short*)d_ws;                 // MPAD*512
    unsigned short* W1T  = xb   + (size_t)MPAD * D_MODEL;         // 2048*512
    unsigned short* W2T  = W1T  + (size_t)NPAD * D_MODEL;         // 512*2048
    unsigned short* hT   = W2T  + (size_t)D_MODEL * NPAD;         // NPAD*MPAD (transposed)
    unsigned short* h2b  = hT   + (size_t)NPAD * MPAD;            // MPAD*NPAD
    unsigned short* img2 = h2b  + (size_t)MPAD * NPAD;            // 800*7524

    cvt_x<<<(MPAD * D_MODEL / 4 + 255) / 256, 256, 0, stream>>>(x, xb);

    dim3 tb(32, 8);
    transpose_cvt<<<dim3(512 / 32, NPAD / 32), tb, 0, stream>>>(W1, W1T, D_MODEL, HD, NPAD, D_MODEL);
    transpose_cvt<<<dim3(NPAD / 32, 512 / 32), tb, 0, stream>>>(W2, W2T, HD, D_MODEL, D_MODEL, NPAD);

    // GEMM1: hT = (xb @ W1T^T + b1)^T   (bf16, transposed out), grid 16x113
    gemm_bt<0><<<dim3(NPAD / 128, MPAD / 128), 256, 0, stream>>>(
        xb, W1T, b1, hT, D_MODEL, 0, HD, MPAD);

    fold_norm<<<dim3(HP, 200), 128, 0, stream>>>(hT, img2);
    unfold_k<<<dim3(400, 2), 256, 0, stream>>>(img2, h2b);

    // GEMM2: out = h2b @ W2T^T + b2  (fp32, rows<14400 only), grid 8x113 = 904 (BN=64)
    gemm_n64<<<dim3(512 / 64, MPAD / 128), 256, 0, stream>>>(
        h2b, W2T, b2, out, NPAD, MROWS);
}

// Round 15
// 183.977 us; speedup vs baseline: 1.1404x; 1.1404x over previous
//
#include <hip/hip_runtime.h>

// ---- problem geometry ----
#define D_MODEL 512
#define HD      1960
#define NPAD    2048          // HD padded to tile multiple
#define NVECS   720
#define MROWS   14400         // 4*3600
#define MPAD    14464         // 113*128 = 226*64
#define HP      66
#define WP      114
#define IMGPIX  7524          // HP*WP

typedef __bf16 bf16x8 __attribute__((ext_vector_type(8)));
typedef float  f32x4  __attribute__((ext_vector_type(4)));

__device__ __forceinline__ unsigned short f2bf(float f) {
    unsigned u = __builtin_bit_cast(unsigned, f);
    u += 0x7FFFu + ((u >> 16) & 1u);   // RNE
    return (unsigned short)(u >> 16);
}
__device__ __forceinline__ float bf2f(unsigned short s) {
    unsigned u = ((unsigned)s) << 16;
    return __builtin_bit_cast(float, u);
}

__device__ __forceinline__ void gload_lds16(const unsigned short* g, unsigned short* l) {
    __builtin_amdgcn_global_load_lds(
        (const __attribute__((address_space(1))) unsigned int*)g,
        (__attribute__((address_space(3))) unsigned int*)l,
        16, 0, 0);
}

// ---- convert x (fp32) -> bf16, zero-pad rows [14400,14464) ----
__global__ void cvt_x(const float* __restrict__ x, unsigned short* __restrict__ xb) {
    size_t i = ((size_t)blockIdx.x * 256 + threadIdx.x) * 4;
    const size_t valid = (size_t)MROWS * D_MODEL;
    if (i >= (size_t)MPAD * D_MODEL) return;
    ushort4 o;
    if (i < valid) {
        float4 v = *(const float4*)(x + i);
        o.x = f2bf(v.x); o.y = f2bf(v.y); o.z = f2bf(v.z); o.w = f2bf(v.w);
    } else {
        o.x = o.y = o.z = o.w = 0;
    }
    *(ushort4*)(xb + i) = o;
}

// ---- tiled transpose + fp32->bf16, zero-fill outside src ----
__global__ void transpose_cvt(const float* __restrict__ src, unsigned short* __restrict__ dst,
                              int srcR, int srcC, int dstR, int dstC) {
    __shared__ float tile[32][33];
    int c0 = blockIdx.x * 32;
    int r0 = blockIdx.y * 32;
    int tx = threadIdx.x, ty = threadIdx.y;   // (32,8)
    #pragma unroll
    for (int i = 0; i < 32; i += 8) {
        int sr = c0 + ty + i, sc = r0 + tx;
        tile[ty + i][tx] = (sr < srcR && sc < srcC) ? src[(size_t)sr * srcC + sc] : 0.f;
    }
    __syncthreads();
    #pragma unroll
    for (int i = 0; i < 32; i += 8) {
        int dr = r0 + ty + i, dc = c0 + tx;
        if (dr < dstR && dc < dstC)
            dst[(size_t)dr * dstC + dc] = f2bf(tile[tx][ty + i]);
    }
}

// ---- 128x128 BK=64 double-buffered counted-vmcnt bf16 GEMM (R12-proven, GEMM1) ----
// MODE 0: out bf16 TRANSPOSED  hT[col*MPAD + row], skip cols >= validN
template<int MODE>
__global__ __launch_bounds__(256) void gemm_bt(const unsigned short* __restrict__ A,
                        const unsigned short* __restrict__ BT,
                        const float* __restrict__ bias,
                        void* __restrict__ Cout,
                        int K, int ldc, int validN, int validM) {
    __shared__ unsigned short lds[2][16384];   // 64KB total
    const int t    = threadIdx.x;
    const int wid  = t >> 6, lane = t & 63;
    const int wr   = wid >> 1, wc = wid & 1;
    const int lr   = lane & 15, lh = lane >> 4;
    const int m0   = blockIdx.y * 128, n0 = blockIdx.x * 128;

    int rr[4], qq[4];
    #pragma unroll
    for (int i = 0; i < 4; ++i) {
        int c = t + i * 256;
        rr[i] = c >> 3;
        qq[i] = (c & 7) ^ (rr[i] & 7);
    }

#define STAGE(buf, kt) do { \
        unsigned short* LA = &lds[buf][0]; \
        unsigned short* LB = &lds[buf][8192]; \
        _Pragma("unroll") \
        for (int i = 0; i < 4; ++i) { \
            gload_lds16(A  + (size_t)(m0 + rr[i]) * K + (kt) + qq[i] * 8, LA + (t + i * 256) * 8); \
            gload_lds16(BT + (size_t)(n0 + rr[i]) * K + (kt) + qq[i] * 8, LB + (t + i * 256) * 8); \
        } \
    } while (0)

    f32x4 acc[4][4] = {};
    const int NT = K >> 6;

    STAGE(0, 0);
    for (int tt = 0; tt < NT; ++tt) {
        if (tt + 1 < NT) {
            STAGE((tt + 1) & 1, (tt + 1) * 64);
            asm volatile("s_waitcnt vmcnt(8)" ::: "memory");
        } else {
            asm volatile("s_waitcnt vmcnt(0)" ::: "memory");
        }
        __builtin_amdgcn_s_barrier();
        __builtin_amdgcn_sched_barrier(0);
        const unsigned short* La = &lds[tt & 1][0];
        const unsigned short* Lb = &lds[tt & 1][8192];
        #pragma unroll
        for (int ks = 0; ks < 2; ++ks) {
            bf16x8 a[4], b[4];
            #pragma unroll
            for (int f = 0; f < 4; ++f) {
                int row = wr * 64 + f * 16 + lr;
                int sl  = (ks * 4 + lh) ^ (lr & 7);
                a[f] = *(const bf16x8*)(La + row * 64 + sl * 8);
            }
            #pragma unroll
            for (int g = 0; g < 4; ++g) {
                int row = wc * 64 + g * 16 + lr;
                int sl  = (ks * 4 + lh) ^ (lr & 7);
                b[g] = *(const bf16x8*)(Lb + row * 64 + sl * 8);
            }
            __builtin_amdgcn_s_setprio(1);
            #pragma unroll
            for (int fm = 0; fm < 4; ++fm)
                #pragma unroll
                for (int fn = 0; fn < 4; ++fn)
                    acc[fm][fn] = __builtin_amdgcn_mfma_f32_16x16x32_bf16(
                        a[fm], b[fn], acc[fm][fn], 0, 0, 0);
            __builtin_amdgcn_s_setprio(0);
        }
        __builtin_amdgcn_s_barrier();
        __builtin_amdgcn_sched_barrier(0);
    }
#undef STAGE

    // C/D layout: col=lane&15, row=(lane>>4)*4+j  [m89 verified]
    if (MODE == 0) {
        unsigned short* smem = &lds[0][0];
        #pragma unroll
        for (int fm = 0; fm < 4; ++fm) {
            #pragma unroll
            for (int fn = 0; fn < 4; ++fn) {
                int lcol = wc * 64 + fn * 16 + lr;
                float bv = bias[n0 + lcol];
                #pragma unroll
                for (int j = 0; j < 4; ++j) {
                    int lrow = wr * 64 + fm * 16 + lh * 4 + j;
                    smem[lcol * 128 + (lrow ^ ((lcol & 15) << 3))] =
                        f2bf(acc[fm][fn][j] + bv);
                }
            }
        }
        __syncthreads();
        unsigned short* hT = (unsigned short*)Cout;
        int col = t >> 1, half = t & 1;
        int gcol = n0 + col;
        if (gcol < validN) {
            #pragma unroll
            for (int r = 0; r < 16; ++r) {
                int row = half * 64 + r * 4;
                ushort4 v4 = *(const ushort4*)&smem[col * 128 + (row ^ ((col & 15) << 3))];
                *(ushort4*)&hT[(size_t)gcol * MPAD + m0 + row] = v4;
            }
        }
    } else {
        #pragma unroll
        for (int fm = 0; fm < 4; ++fm) {
            #pragma unroll
            for (int fn = 0; fn < 4; ++fn) {
                int gcol = n0 + wc * 64 + fn * 16 + lr;
                float bv = bias[gcol];
                #pragma unroll
                for (int j = 0; j < 4; ++j) {
                    int grow = m0 + wr * 64 + fm * 16 + lh * 4 + j;
                    if (grow < validM)
                        ((float*)Cout)[(size_t)grow * ldc + gcol] = acc[fm][fn][j] + bv;
                }
            }
        }
    }
}

// ---- 64x128 BK=64 counted-vmcnt bf16 GEMM for GEMM2 (BM=64: 3 blocks/CU, A-reuse x4 kept) ----
// C = A(MxK) * BT(NxK)^T + bias, fp32 row-major out (ldc=512), skip rows >= validM.
// 4 waves (2x2), wave tile 32(m) x 64(n), acc 2x4. LDS 48KB = 2 bufs x [A 8KB | B 16KB],
// slot-XOR layout; staging 6 loads/thread (A:2, B:4); vmcnt(6) counted in-loop.
__global__ __launch_bounds__(256) void gemm_m64(const unsigned short* __restrict__ A,
                        const unsigned short* __restrict__ BT,
                        const float* __restrict__ bias,
                        float* __restrict__ out,
                        int K, int validM) {
    __shared__ unsigned short lds[2][12288];   // 48KB total
    const int t    = threadIdx.x;
    const int wid  = t >> 6, lane = t & 63;
    const int wr   = wid >> 1, wc = wid & 1;
    const int lr   = lane & 15, lh = lane >> 4;
    const int m0   = blockIdx.y * 64, n0 = blockIdx.x * 128;

    // A tile: 512 chunks (64 rows x 8 slots); thread owns c = t, t+256
    int rA[2], qA[2];
    #pragma unroll
    for (int i = 0; i < 2; ++i) {
        int c = t + i * 256;
        rA[i] = c >> 3;
        qA[i] = (c & 7) ^ (rA[i] & 7);
    }
    // B tile: 1024 chunks (128 rows x 8 slots); thread owns c = t + i*256, i=0..3
    int rB[4], qB[4];
    #pragma unroll
    for (int i = 0; i < 4; ++i) {
        int c = t + i * 256;
        rB[i] = c >> 3;
        qB[i] = (c & 7) ^ (rB[i] & 7);
    }

#define STAGE64(buf, kt) do { \
        unsigned short* LA = &lds[buf][0]; \
        unsigned short* LB = &lds[buf][4096]; \
        _Pragma("unroll") \
        for (int i = 0; i < 2; ++i) \
            gload_lds16(A  + (size_t)(m0 + rA[i]) * K + (kt) + qA[i] * 8, LA + (t + i * 256) * 8); \
        _Pragma("unroll") \
        for (int i = 0; i < 4; ++i) \
            gload_lds16(BT + (size_t)(n0 + rB[i]) * K + (kt) + qB[i] * 8, LB + (t + i * 256) * 8); \
    } while (0)

    f32x4 acc[2][4] = {};
    const int NT = K >> 6;

    STAGE64(0, 0);
    for (int tt = 0; tt < NT; ++tt) {
        if (tt + 1 < NT) {
            STAGE64((tt + 1) & 1, (tt + 1) * 64);
            asm volatile("s_waitcnt vmcnt(6)" ::: "memory");
        } else {
            asm volatile("s_waitcnt vmcnt(0)" ::: "memory");
        }
        __builtin_amdgcn_s_barrier();
        __builtin_amdgcn_sched_barrier(0);
        const unsigned short* La = &lds[tt & 1][0];
        const unsigned short* Lb = &lds[tt & 1][4096];
        #pragma unroll
        for (int ks = 0; ks < 2; ++ks) {
            bf16x8 a[2], b[4];
            #pragma unroll
            for (int f = 0; f < 2; ++f) {
                int row = wr * 32 + f * 16 + lr;
                int sl  = (ks * 4 + lh) ^ (lr & 7);
                a[f] = *(const bf16x8*)(La + row * 64 + sl * 8);
            }
            #pragma unroll
            for (int g = 0; g < 4; ++g) {
                int row = wc * 64 + g * 16 + lr;
                int sl  = (ks * 4 + lh) ^ (lr & 7);
                b[g] = *(const bf16x8*)(Lb + row * 64 + sl * 8);
            }
            __builtin_amdgcn_s_setprio(1);
            #pragma unroll
            for (int fm = 0; fm < 2; ++fm)
                #pragma unroll
                for (int fn = 0; fn < 4; ++fn)
                    acc[fm][fn] = __builtin_amdgcn_mfma_f32_16x16x32_bf16(
                        a[fm], b[fn], acc[fm][fn], 0, 0, 0);
            __builtin_amdgcn_s_setprio(0);
        }
        __builtin_amdgcn_s_barrier();
        __builtin_amdgcn_sched_barrier(0);
    }
#undef STAGE64

    // C/D layout: col=lane&15, row=(lane>>4)*4+j
    #pragma unroll
    for (int fm = 0; fm < 2; ++fm) {
        #pragma unroll
        for (int fn = 0; fn < 4; ++fn) {
            int gcol = n0 + wc * 64 + fn * 16 + lr;
            float bv = bias[gcol];
            #pragma unroll
            for (int j = 0; j < 4; ++j) {
                int grow = m0 + wr * 32 + fm * 16 + lh * 4 + j;
                if (grow < validM)
                    out[(size_t)grow * 512 + gcol] = acc[fm][fn][j] + bv;
            }
        }
    }
}

// ---- fold + normalize + relu -> per-(b2,c) padded image (bf16) ----
__global__ void fold_norm(const unsigned short* __restrict__ hT, unsigned short* __restrict__ img2) {
    int y  = blockIdx.x;
    int g  = blockIdx.y;
    int b2 = g / 10, cg = g % 10;
    int c0 = cg * 4;
    int x  = threadIdx.x;
    if (x >= WP) return;
    float val[4] = {0.f, 0.f, 0.f, 0.f};
    if (y >= 3 && y < 63 && x >= 3 && x < 111) {
        int kiA[3], biA[3], nki = 0;
        for (int ki = y % 3; ki < 7; ki += 3) {
            int bi = (y - ki) / 3;
            if (y - ki >= 0 && bi < 20) { kiA[nki] = ki; biA[nki] = bi; ++nki; }
        }
        int kjA[3], bjA[3], nkj = 0;
        for (int kj = x % 3; kj < 7; kj += 3) {
            int bj = (x - kj) / 3;
            if (x - kj >= 0 && bj < 36) { kjA[nkj] = kj; bjA[nkj] = bj; ++nkj; }
        }
        float s[4] = {0.f, 0.f, 0.f, 0.f};
        for (int i = 0; i < nki; ++i) {
            for (int j = 0; j < nkj; ++j) {
                int row = b2 * NVECS + biA[i] * 36 + bjA[j];
                int colb = kiA[i] * 7 + kjA[j];
                #pragma unroll
                for (int q = 0; q < 4; ++q)
                    s[q] += bf2f(hT[(size_t)((c0 + q) * 49 + colb) * MPAD + row]);
            }
        }
        float inv = 1.f / (float)(nki * nkj);
        #pragma unroll
        for (int q = 0; q < 4; ++q)
            val[q] = fmaxf(s[q] * inv, 0.f);
    }
    #pragma unroll
    for (int q = 0; q < 4; ++q)
        img2[(size_t)(b2 * 40 + c0 + q) * IMGPIX + y * WP + x] = f2bf(val[q]);
}

// ---- unfold, LDS-staged ----
__global__ void unfold_k(const unsigned short* __restrict__ img2, unsigned short* __restrict__ h2b) {
    __shared__ unsigned short lds[20 * 798];
    __shared__ unsigned short lut[980];
    const int gb = blockIdx.x;                 // b2*20 + bi
    const int cg = blockIdx.y;
    const int b2 = gb / 20, bi = gb % 20;
    const int t  = threadIdx.x;

    const unsigned short* src = img2 + (size_t)(b2 * 40 + cg * 20) * IMGPIX + (bi * 3) * WP;
    for (int p = t; p < 7980; p += 256) {
        int cc = p / 399, rem2 = p - cc * 399;
        *(ushort2*)&lds[cc * 798 + rem2 * 2] =
            *(const ushort2*)&src[(size_t)cc * IMGPIX + rem2 * 2];
    }
    for (int L = t; L < 980; L += 256) {
        int cc = L / 49, kk = L - cc * 49;
        lut[L] = (unsigned short)(cc * 798 + (kk / 7) * 114 + (kk % 7));
    }
    __syncthreads();

    const int cpr   = (cg == 0) ? 245 : 267;
    const int total = 36 * cpr;
    const int rowbase = b2 * NVECS + bi * 36;
    const int hdbase  = cg * 980;
    for (int i = t; i < total; i += 256) {
        int r = i / cpr, q = i - r * cpr;
        int hl = q * 4;
        ushort4 v;
        unsigned short* vv = (unsigned short*)&v;
        #pragma unroll
        for (int e = 0; e < 4; ++e) {
            int h = hl + e;
            vv[e] = (h < 980) ? lds[lut[h] + r * 3] : (unsigned short)0;
        }
        *(ushort4*)&h2b[(size_t)(rowbase + r) * NPAD + hdbase + hl] = v;
    }
}

extern "C" void kernel_launch(void* const* d_in, const int* in_sizes, int n_in,
                              void* d_out, int out_size, void* d_ws, size_t ws_size,
                              hipStream_t stream) {
    const float* x  = (const float*)d_in[0];
    const float* W1 = (const float*)d_in[1];
    const float* b1 = (const float*)d_in[2];
    const float* W2 = (const float*)d_in[3];
    const float* b2 = (const float*)d_in[4];
    float* out = (float*)d_out;

    unsigned short* xb   = (unsigned short*)d_ws;                 // MPAD*512
    unsigned short* W1T  = xb   + (size_t)MPAD * D_MODEL;         // 2048*512
    unsigned short* W2T  = W1T  + (size_t)NPAD * D_MODEL;         // 512*2048
    unsigned short* hT   = W2T  + (size_t)D_MODEL * NPAD;         // NPAD*MPAD (transposed)
    unsigned short* h2b  = hT   + (size_t)NPAD * MPAD;            // MPAD*NPAD
    unsigned short* img2 = h2b  + (size_t)MPAD * NPAD;            // 800*7524

    cvt_x<<<(MPAD * D_MODEL / 4 + 255) / 256, 256, 0, stream>>>(x, xb);

    dim3 tb(32, 8);
    transpose_cvt<<<dim3(512 / 32, NPAD / 32), tb, 0, stream>>>(W1, W1T, D_MODEL, HD, NPAD, D_MODEL);
    transpose_cvt<<<dim3(NPAD / 32, 512 / 32), tb, 0, stream>>>(W2, W2T, HD, D_MODEL, D_MODEL, NPAD);

    // GEMM1: hT = (xb @ W1T^T + b1)^T   (bf16, transposed out), grid 16x113
    gemm_bt<0><<<dim3(NPAD / 128, MPAD / 128), 256, 0, stream>>>(
        xb, W1T, b1, hT, D_MODEL, 0, HD, MPAD);

    fold_norm<<<dim3(HP, 200), 128, 0, stream>>>(hT, img2);
    unfold_k<<<dim3(400, 2), 256, 0, stream>>>(img2, h2b);

    // GEMM2: out = h2b @ W2T^T + b2  (fp32, rows<14400 only), grid 4x226 = 904 (BM=64)
    gemm_m64<<<dim3(512 / 128, MPAD / 64), 256, 0, stream>>>(
        h2b, W2T, b2, out, NPAD, MROWS);
}